// Round 8
// baseline (76.917 us; speedup 1.0000x reference)
//
#include <hip/hip_runtime.h>
#include <cstdint>
#include <cstddef>

// ---------------------------------------------------------------------------
// B=4, N=1024, C=256, H=8, hd=32, ALPHA=0.6
// softmax rows sum to 1 => S_x = attn_x^T; associativity kills the N^3 work.
// r8: dual-fragment waves. fused1: each wave owns 32 q (2 x 16-frags) so the
// shared K/V LDS fragments are read ONCE per two MFMAs (per-wave LDS reads
// 56 -> 32 per 32q). fused2: each wave owns 32 n (2 frags), sharing qa/Os
// reads. Grids (64,4); staging/sync structure identical to passing r7.
// ---------------------------------------------------------------------------

typedef _Float16 f16;
typedef _Float16 half8 __attribute__((ext_vector_type(8)));
typedef float f32x4 __attribute__((ext_vector_type(4)));

#define ALPHA_F 0.6f
#define OMA_F   0.4f
#define SCALE_L2E 0.25503482f  // (1/sqrt(32)) * log2(e)

static const size_t WS_QKVH = 0;               // 8192*768*2   = 12,582,912
static const size_t WS_VT   = 12582912ull;     // 32*64*1024*2 =  4,194,304
static const size_t WS_OT   = 16777216ull;     // 64*64*1024*2 =  8,388,608
static const size_t WS_RS   = 25165824ull;     // 64*1024*4    =    262,144

__device__ __forceinline__ uint4 pack8(float4 a, float4 b) {
  union { f16 h[8]; uint4 u; } pk;
  pk.h[0] = (f16)a.x; pk.h[1] = (f16)a.y; pk.h[2] = (f16)a.z; pk.h[3] = (f16)a.w;
  pk.h[4] = (f16)b.x; pk.h[5] = (f16)b.y; pk.h[6] = (f16)b.z; pk.h[7] = (f16)b.w;
  return pk.u;
}

// ---------------------------------------------------------------------------
// K1: proj MFMA GEMM, LDS-staged, f32 inputs cast in staging (unchanged r7).
__global__ __launch_bounds__(512) void k_projm(const float* __restrict__ x,
                                               const float* __restrict__ wr,
                                               const float* __restrict__ wd,
                                               f16* __restrict__ qkvh,
                                               f16* __restrict__ VT) {
  __shared__ f16 Ws[64][264];
  __shared__ f16 Xs[2][128][40];
  __shared__ f16 sc[8][64][24];
  const int t = threadIdx.x;
  const int w = t >> 6, l = t & 63, g = l >> 4, li = l & 15;
  const int m0 = blockIdx.x * 128;
  const int j0 = blockIdx.y * 64;
  const int br = m0 >> 12;
  const int mrow = m0 & 4095;
  const bool qk = (j0 < 512);
  const float* wsrc = br ? wd : wr;
#pragma unroll
  for (int ps = 0; ps < 4; ++ps) {
    const int idx = ps * 512 + t;
    const int wrow = idx >> 5, wc8 = (idx & 31) * 8;
    const float* s = wsrc + (size_t)(j0 + wrow) * 256 + wc8;
    *(uint4*)&Ws[wrow][wc8] = pack8(*(const float4*)s, *(const float4*)(s + 4));
  }
  const int xrow = t >> 2, xc8 = (t & 3) * 8;
  const float* xgl = x + (size_t)(mrow + xrow) * 512 + br * 256 + xc8;
  float4 xr0 = *(const float4*)xgl;
  float4 xr1 = *(const float4*)(xgl + 4);
  *(uint4*)&Xs[0][xrow][xc8] = pack8(xr0, xr1);
  const f32x4 z = {0.f, 0.f, 0.f, 0.f};
  f32x4 c[4] = {z, z, z, z};
  int cur = 0;
  for (int kc = 0; kc < 8; ++kc, cur ^= 1) {
    __syncthreads();
    if (kc < 7) {
      xr0 = *(const float4*)(xgl + (kc + 1) * 32);
      xr1 = *(const float4*)(xgl + (kc + 1) * 32 + 4);
    }
    half8 xa = *(const half8*)&Xs[cur][w * 16 + li][8 * g];
    if (qk) {
#pragma unroll
      for (int jf = 0; jf < 4; ++jf) {
        half8 wa = *(const half8*)&Ws[jf * 16 + li][kc * 32 + 8 * g];
        c[jf] = __builtin_amdgcn_mfma_f32_16x16x32_f16(wa, xa, c[jf], 0, 0, 0);
      }
    } else {
#pragma unroll
      for (int jf = 0; jf < 4; ++jf) {
        half8 wa = *(const half8*)&Ws[jf * 16 + li][kc * 32 + 8 * g];
        c[jf] = __builtin_amdgcn_mfma_f32_16x16x32_f16(xa, wa, c[jf], 0, 0, 0);
      }
    }
    if (kc < 7) *(uint4*)&Xs[cur ^ 1][xrow][xc8] = pack8(xr0, xr1);
  }
  if (qk) {
    f16 (*Qw)[72] = (f16(*)[72])&sc[w][0][0];
#pragma unroll
    for (int jf = 0; jf < 4; ++jf) {
      union { f16 h[4]; uint2 u; } pk;
#pragma unroll
      for (int r = 0; r < 4; ++r) pk.h[r] = (f16)c[jf][r];
      *(uint2*)&Qw[li][jf * 16 + 4 * g] = pk.u;
    }
    const int n = l >> 2, jc = (l & 3) * 16;
    uint4 v0 = *(const uint4*)&Qw[n][jc];
    uint4 v1 = *(const uint4*)&Qw[n][jc + 8];
    f16* dst = qkvh + (size_t)(m0 + w * 16 + n) * 768 + j0 + jc;
    *(uint4*)dst = v0;
    *(uint4*)(dst + 8) = v1;
  } else {
    f16 (*Vw)[24] = (f16(*)[24])&sc[w][0][0];
#pragma unroll
    for (int jf = 0; jf < 4; ++jf) {
      union { f16 h[4]; uint2 u; } pk;
#pragma unroll
      for (int r = 0; r < 4; ++r) pk.h[r] = (f16)c[jf][r];
      *(uint2*)&Vw[jf * 16 + li][4 * g] = pk.u;
    }
    const int jg = j0 + l - 512;
    const int hh = jg >> 5, dd = jg & 31;
    const int b = mrow >> 10;
    const int nn = (mrow & 1023) + w * 16;
    uint4 v0 = *(const uint4*)&Vw[l][0];
    uint4 v1 = *(const uint4*)&Vw[l][8];
    f16* dst = VT + ((size_t)(b * 8 + hh) * 64 + br * 32 + dd) * 1024 + nn;
    *(uint4*)dst = v0;
    *(uint4*)(dst + 8) = v1;
  }
}

// ---------------------------------------------------------------------------
// K2: fused flash pass, dual q-frag waves (32 q/wave).  Grid (64,4).
__global__ __launch_bounds__(512) void k_fused1(const f16* __restrict__ qkvh,
                                                const f16* __restrict__ VT,
                                                f16* __restrict__ OT,
                                                float* __restrict__ rsums,
                                                float* __restrict__ out) {
  __shared__ f16 Ks[2][128][40];
  __shared__ f16 Vs[2][64][136];
  __shared__ f16 scw[8][2560];   // per-wave: P0[16][72] | P1[16][72]; reuse Ow[64][40]
  __shared__ float rsh[8][32];
  const int t = threadIdx.x;
  const int bb = blockIdx.x;
  const int br = bb >> 5, bh = bb & 31, b = bh >> 3, h = bh & 7;
  const int w = t >> 6, l = t & 63, g = l >> 4, li = l & 15;
  const int q0 = blockIdx.y * 256 + w * 32;
  const size_t rowbase = (size_t)(br * 4096 + b * 1024) * 768;
  half8 qf0 = *(const half8*)(qkvh + rowbase + (size_t)(q0 + li) * 768 + h * 32 + 8 * g);
  half8 qf1 = *(const half8*)(qkvh + rowbase + (size_t)(q0 + 16 + li) * 768 + h * 32 + 8 * g);
  const int krow = t >> 2, kc8 = (t & 3) * 8;
  const int vrow = t >> 3, vc8 = (t & 7) * 8;
  const f16* kgl = qkvh + rowbase + (size_t)krow * 768 + 256 + h * 32 + kc8;
  const f16* vgl = VT + ((size_t)bh * 64 + vrow) * 1024 + vc8;
  uint4 kreg = *(const uint4*)kgl;
  uint4 vreg0 = *(const uint4*)vgl;
  uint4 vreg1 = *(const uint4*)(vgl + 64);
  *(uint4*)&Ks[0][krow][kc8] = kreg;
  *(uint4*)&Vs[0][vrow][vc8] = vreg0;
  *(uint4*)&Vs[0][vrow][64 + vc8] = vreg1;
  f16 (*P0)[72] = (f16(*)[72])&scw[w][0];
  f16 (*P1)[72] = (f16(*)[72])&scw[w][1152];
  const f32x4 z = {0.f, 0.f, 0.f, 0.f};
  f32x4 o0[4] = {z, z, z, z};
  f32x4 o1[4] = {z, z, z, z};
  float qsum0 = 0.f, qsum1 = 0.f;
  int cur = 0;
  for (int tile = 0; tile < 8; ++tile, cur ^= 1) {
    __syncthreads();
    if (tile < 7) {
      const int m1 = (tile + 1) * 128;
      kreg = *(const uint4*)(kgl + (size_t)m1 * 768);
      vreg0 = *(const uint4*)(vgl + m1);
      vreg1 = *(const uint4*)(vgl + m1 + 64);
    }
#pragma unroll
    for (int kh = 0; kh < 2; ++kh) {
      f32x4 s0[4], s1[4];
#pragma unroll
      for (int ct = 0; ct < 4; ++ct) {
        half8 ka = *(const half8*)&Ks[cur][kh * 64 + ct * 16 + li][8 * g];
        s0[ct] = __builtin_amdgcn_mfma_f32_16x16x32_f16(ka, qf0, z, 0, 0, 0);
        s1[ct] = __builtin_amdgcn_mfma_f32_16x16x32_f16(ka, qf1, z, 0, 0, 0);
      }
#pragma unroll
      for (int ct = 0; ct < 4; ++ct) {
        union { f16 hh[4]; uint2 u; } pk0, pk1;
#pragma unroll
        for (int r = 0; r < 4; ++r) {
          float p0 = exp2f(s0[ct][r] * SCALE_L2E);
          float p1 = exp2f(s1[ct][r] * SCALE_L2E);
          qsum0 += p0; qsum1 += p1;
          pk0.hh[r] = (f16)p0; pk1.hh[r] = (f16)p1;
        }
        *(uint2*)&P0[li][ct * 16 + 4 * g] = pk0.u;
        *(uint2*)&P1[li][ct * 16 + 4 * g] = pk1.u;
      }
#pragma unroll
      for (int kk = 0; kk < 2; ++kk) {
        half8 pa0 = *(const half8*)&P0[li][kk * 32 + 8 * g];
        half8 pa1 = *(const half8*)&P1[li][kk * 32 + 8 * g];
#pragma unroll
        for (int jf = 0; jf < 4; ++jf) {
          half8 vv = *(const half8*)&Vs[cur][jf * 16 + li][kh * 64 + kk * 32 + 8 * g];
          o0[jf] = __builtin_amdgcn_mfma_f32_16x16x32_f16(pa0, vv, o0[jf], 0, 0, 0);
          o1[jf] = __builtin_amdgcn_mfma_f32_16x16x32_f16(pa1, vv, o1[jf], 0, 0, 0);
        }
      }
    }
    if (tile < 7) {
      *(uint4*)&Ks[cur ^ 1][krow][kc8] = kreg;
      *(uint4*)&Vs[cur ^ 1][vrow][vc8] = vreg0;
      *(uint4*)&Vs[cur ^ 1][vrow][64 + vc8] = vreg1;
    }
  }
  qsum0 += __shfl_xor(qsum0, 16, 64);
  qsum0 += __shfl_xor(qsum0, 32, 64);
  qsum1 += __shfl_xor(qsum1, 16, 64);
  qsum1 += __shfl_xor(qsum1, 32, 64);
  const float rinv0 = 1.0f / qsum0;
  const float rinv1 = 1.0f / qsum1;
  if (l < 16) {
    rsh[w][li] = rinv0;
    rsh[w][16 + li] = rinv1;
    rsums[(size_t)bb * 1024 + q0 + li] = rinv0;
    rsums[(size_t)bb * 1024 + q0 + 16 + li] = rinv1;
  }
  float rv0[4], rv1[4];
#pragma unroll
  for (int r = 0; r < 4; ++r) {
    rv0[r] = rsh[w][4 * g + r];
    rv1[r] = rsh[w][16 + 4 * g + r];
  }
#pragma unroll
  for (int jf = 0; jf < 4; ++jf)
#pragma unroll
    for (int r = 0; r < 4; ++r) {
      o0[jf][r] *= rv0[r];
      o1[jf][r] *= rv1[r];
    }
  // ---- out_r / out_d straight from registers (both frags) ----
  {
    const int jf0 = br * 2;
    float* ob0 = out + ((size_t)((2 + br) * 4 + b) * 1024 + q0 + 4 * g) * 256 + h * 32 + li;
    float* ob1 = out + ((size_t)((2 + br) * 4 + b) * 1024 + q0 + 16 + 4 * g) * 256 + h * 32 + li;
#pragma unroll
    for (int jf2 = 0; jf2 < 2; ++jf2)
#pragma unroll
      for (int r = 0; r < 4; ++r) {
        ob0[(size_t)r * 256 + jf2 * 16] = o0[jf0 + jf2][r];
        ob1[(size_t)r * 256 + jf2 * 16] = o1[jf0 + jf2][r];
      }
  }
  // ---- transpose O (32q x 64j) -> Ow[j][q] rows [64][40], then OT ----
  f16 (*Ow)[40] = (f16(*)[40])&scw[w][0];
#pragma unroll
  for (int jf = 0; jf < 4; ++jf)
#pragma unroll
    for (int rp = 0; rp < 2; ++rp) {
      union { f16 h[2]; unsigned int u; } a0, a1;
      a0.h[0] = (f16)o0[jf][2 * rp]; a0.h[1] = (f16)o0[jf][2 * rp + 1];
      a1.h[0] = (f16)o1[jf][2 * rp]; a1.h[1] = (f16)o1[jf][2 * rp + 1];
      *(unsigned int*)&Ow[jf * 16 + li][4 * g + 2 * rp] = a0.u;
      *(unsigned int*)&Ow[jf * 16 + li][16 + 4 * g + 2 * rp] = a1.u;
    }
  {
    f16* dst = OT + ((size_t)bb * 64 + l) * 1024 + q0;
    uint4 v0 = *(const uint4*)&Ow[l][0];
    uint4 v1 = *(const uint4*)&Ow[l][8];
    uint4 v2 = *(const uint4*)&Ow[l][16];
    uint4 v3 = *(const uint4*)&Ow[l][24];
    *(uint4*)dst = v0;
    *(uint4*)(dst + 8) = v1;
    *(uint4*)(dst + 16) = v2;
    *(uint4*)(dst + 24) = v3;
  }
}

// ---------------------------------------------------------------------------
// K3: fused recompute + U + combine, dual n-frag waves (32 n/wave). Grid (64,4).
__global__ __launch_bounds__(512) void k_fused2(const f16* __restrict__ qkvh,
                                                const f16* __restrict__ OT,
                                                const float* __restrict__ rsums,
                                                float* __restrict__ out) {
  __shared__ f16 Qs[2][128][40];
  __shared__ f16 Os[2][32][136];
  __shared__ f16 sc2h[8][4352];  // per-wave: P0[16][136] | P1[16][136]; reuse Uw0/Uw1
  __shared__ float rb[1024];
  const int t = threadIdx.x;
  const int pb = blockIdx.x;
  const int p = pb >> 5, bh = pb & 31, b = bh >> 3, h = bh & 7;
  const int w = t >> 6, l = t & 63, g = l >> 4, li = l & 15;
  const int n0 = blockIdx.y * 256 + w * 32;
  const int abb = p * 32 + bh;
  const int obb = p ? bh : 32 + bh;
  const int aoff = p ? 0 : 32;
  const size_t rowbase = (size_t)(p * 4096 + b * 1024) * 768;
  rb[t] = rsums[(size_t)abb * 1024 + t];
  rb[t + 512] = rsums[(size_t)abb * 1024 + t + 512];
  half8 kf0 = *(const half8*)(qkvh + rowbase + (size_t)(n0 + li) * 768 + 256 + h * 32 + 8 * g);
  half8 kf1 = *(const half8*)(qkvh + rowbase + (size_t)(n0 + 16 + li) * 768 + 256 + h * 32 + 8 * g);
  const int qrow = t >> 2, qc8 = (t & 3) * 8;
  const int orow = t >> 4, oc8 = (t & 15) * 8;
  const f16* qgl = qkvh + rowbase + (size_t)qrow * 768 + h * 32 + qc8;
  const f16* ogl = OT + ((size_t)obb * 64 + aoff + orow) * 1024 + oc8;
  uint4 qreg = *(const uint4*)qgl;
  uint4 oreg = *(const uint4*)ogl;
  *(uint4*)&Qs[0][qrow][qc8] = qreg;
  *(uint4*)&Os[0][orow][oc8] = oreg;
  f16 (*P0)[136] = (f16(*)[136])&sc2h[w][0];
  f16 (*P1)[136] = (f16(*)[136])&sc2h[w][2176];
  const f32x4 z = {0.f, 0.f, 0.f, 0.f};
  f32x4 u00 = z, u01 = z, u10 = z, u11 = z;
  int cur = 0;
  for (int tile = 0; tile < 8; ++tile, cur ^= 1) {
    __syncthreads();
    if (tile < 7) {
      const int q1 = (tile + 1) * 128;
      qreg = *(const uint4*)(qgl + (size_t)q1 * 768);
      oreg = *(const uint4*)(ogl + q1);
    }
    const int qt0 = tile * 128;
#pragma unroll
    for (int fq = 0; fq < 8; ++fq) {
      half8 qa = *(const half8*)&Qs[cur][fq * 16 + li][8 * g];
      f32x4 s0 = __builtin_amdgcn_mfma_f32_16x16x32_f16(qa, kf0, z, 0, 0, 0);
      f32x4 s1 = __builtin_amdgcn_mfma_f32_16x16x32_f16(qa, kf1, z, 0, 0, 0);
      union { f16 hh[4]; uint2 u; } pk0, pk1;
#pragma unroll
      for (int r = 0; r < 4; ++r) {
        const float rr = rb[qt0 + fq * 16 + 4 * g + r];
        pk0.hh[r] = (f16)(exp2f(s0[r] * SCALE_L2E) * rr);
        pk1.hh[r] = (f16)(exp2f(s1[r] * SCALE_L2E) * rr);
      }
      *(uint2*)&P0[li][fq * 16 + 4 * g] = pk0.u;
      *(uint2*)&P1[li][fq * 16 + 4 * g] = pk1.u;
    }
#pragma unroll
    for (int kk = 0; kk < 4; ++kk) {
      half8 pb0 = *(const half8*)&P0[li][kk * 32 + 8 * g];
      half8 pb1 = *(const half8*)&P1[li][kk * 32 + 8 * g];
      half8 A0 = *(const half8*)&Os[cur][li][kk * 32 + 8 * g];
      half8 A1 = *(const half8*)&Os[cur][16 + li][kk * 32 + 8 * g];
      u00 = __builtin_amdgcn_mfma_f32_16x16x32_f16(A0, pb0, u00, 0, 0, 0);
      u01 = __builtin_amdgcn_mfma_f32_16x16x32_f16(A1, pb0, u01, 0, 0, 0);
      u10 = __builtin_amdgcn_mfma_f32_16x16x32_f16(A0, pb1, u10, 0, 0, 0);
      u11 = __builtin_amdgcn_mfma_f32_16x16x32_f16(A1, pb1, u11, 0, 0, 0);
    }
    if (tile < 7) {
      *(uint4*)&Qs[cur ^ 1][qrow][qc8] = qreg;
      *(uint4*)&Os[cur ^ 1][orow][oc8] = oreg;
    }
  }
  // combine: alpha*U + 0.4*(OT[bh] + OT[32+bh]) rows aoff+d  (both frags)
  float (*Uw0)[36] = (float(*)[36])&sc2h[w][0];
  float (*Uw1)[36] = (float(*)[36])&sc2h[w][2176];
#pragma unroll
  for (int df = 0; df < 2; ++df)
#pragma unroll
    for (int r = 0; r < 4; ++r) {
      const int d_l = df * 16 + 4 * g + r;
      const size_t rowr = ((size_t)bh * 64 + aoff + d_l) * 1024;
      const size_t rowd = ((size_t)(32 + bh) * 64 + aoff + d_l) * 1024;
      float uu0 = df ? u01[r] : u00[r];
      float uu1 = df ? u11[r] : u10[r];
      float a10 = (float)OT[rowr + n0 + li];
      float a20 = (float)OT[rowd + n0 + li];
      float a11 = (float)OT[rowr + n0 + 16 + li];
      float a21 = (float)OT[rowd + n0 + 16 + li];
      Uw0[li][d_l] = ALPHA_F * uu0 + OMA_F * (a10 + a20);
      Uw1[li][d_l] = ALPHA_F * uu1 + OMA_F * (a11 + a21);
    }
  const int nn = l >> 2, dq = (l & 3) * 8;
  {
    f32x4 v0 = *(const f32x4*)&Uw0[nn][dq];
    f32x4 v1 = *(const f32x4*)&Uw0[nn][dq + 4];
    float* dst = out + ((size_t)((1 - p) * 4 + b) * 1024 + n0 + nn) * 256 + h * 32 + dq;
    *(f32x4*)dst = v0;
    *(f32x4*)(dst + 4) = v1;
  }
  {
    f32x4 v0 = *(const f32x4*)&Uw1[nn][dq];
    f32x4 v1 = *(const f32x4*)&Uw1[nn][dq + 4];
    float* dst = out + ((size_t)((1 - p) * 4 + b) * 1024 + n0 + 16 + nn) * 256 + h * 32 + dq;
    *(f32x4*)dst = v0;
    *(f32x4*)(dst + 4) = v1;
  }
}

// ---------------------------------------------------------------------------
extern "C" void kernel_launch(void* const* d_in, const int* in_sizes, int n_in,
                              void* d_out, int out_size, void* d_ws, size_t ws_size,
                              hipStream_t stream) {
  const float* x  = (const float*)d_in[0];
  const float* wr = (const float*)d_in[1];
  const float* wd = (const float*)d_in[2];
  float* out = (float*)d_out;
  char* ws = (char*)d_ws;
  f16* qkvh  = (f16*)(ws + WS_QKVH);
  f16* VT    = (f16*)(ws + WS_VT);
  f16* OT    = (f16*)(ws + WS_OT);
  float* rsums = (float*)(ws + WS_RS);

  k_projm<<<dim3(64, 12), 512, 0, stream>>>(x, wr, wd, qkvh, VT);
  k_fused1<<<dim3(64, 4), 512, 0, stream>>>(qkvh, VT, OT, rsums, out);
  k_fused2<<<dim3(64, 4), 512, 0, stream>>>(qkvh, OT, rsums, out);
}